// Round 7
// baseline (211.996 us; speedup 1.0000x reference)
//
#include <hip/hip_runtime.h>
#include <hip/hip_bf16.h>

// Shapes: B=4, LQ=LKV=1024, D=1024, H=16, HD=64, N=H*HD=1024, M=B*LQ=4096
// Inputs  (f32): queries[4,1024,1024], context[4,1024,1024],
//   Wq/Wk/Wv[16,1024,64], bq/bk/bv[16,64], Wo[1024,1024], bo[1024]
// Outputs (f32, concat): out[4,1024,1024], residual[4,1024,1024]
// ws (u16, 56 MB): Aq 4M | Ac 4M | Wqt 1M | Wkt 1M | Wvt 1M | Wot 1M |
//                  qws 4M (x0.125) | kws 4M | vtws 4M (dim-major) | mws 4M

typedef unsigned short u16;
typedef __attribute__((ext_vector_type(8))) short short8;   // 8 bf16 = 4 VGPRs
typedef __attribute__((ext_vector_type(4))) float f32x4;

__device__ __forceinline__ float bf2f(u16 u) {
    union { unsigned int i; float f; } c;
    c.i = ((unsigned int)u) << 16;
    return c.f;
}

__device__ __forceinline__ u16 f2bf(float f) {
    unsigned int x = __float_as_uint(f);
    unsigned int r = (x + 0x7fffu + ((x >> 16) & 1u)) >> 16;  // RNE
    return (u16)r;
}

// async global->LDS, 16B per lane; LDS dest = wave-uniform base + lane*16
__device__ __forceinline__ void glds16(u16* lds, const u16* g) {
    __builtin_amdgcn_global_load_lds(
        (const __attribute__((address_space(1))) void*)g,
        (__attribute__((address_space(3))) void*)lds, 16, 0, 0);
}

// ---------------------------------------------------------------------------
// Fused pre-pass, flat grid 5120 blocks x 256 thr:
//  [0,4096):   cast queries+context f32 -> bf16 row-major (8 elem/thread)
//  [4096,4864): transpose+cast Wq/Wk/Wv [16][1024][64] -> [16][64][1024]
//  [4864,5120): transpose+cast Wo [1024][1024] -> [1024][1024] (n-major)
// ---------------------------------------------------------------------------
__global__ __launch_bounds__(256) void prep(
    const float* __restrict__ q, const float* __restrict__ ctx,
    const float* __restrict__ Wq, const float* __restrict__ Wk,
    const float* __restrict__ Wv, const float* __restrict__ Wo,
    u16* __restrict__ Aq, u16* __restrict__ Ac,
    u16* __restrict__ Wqt, u16* __restrict__ Wkt,
    u16* __restrict__ Wvt, u16* __restrict__ Wot)
{
    __shared__ float ls[64][65];
    const int t = threadIdx.x;
    int bid = blockIdx.x;

    if (bid < 4096) {
        const float* in = (bid < 2048) ? q : ctx;
        u16* out = (bid < 2048) ? Aq : Ac;
        size_t i = ((size_t)(bid & 2047) * 256 + t) * 8;
        float4 v0 = *(const float4*)(in + i);
        float4 v1 = *(const float4*)(in + i + 4);
        short8 p;
        p[0] = (short)f2bf(v0.x); p[1] = (short)f2bf(v0.y);
        p[2] = (short)f2bf(v0.z); p[3] = (short)f2bf(v0.w);
        p[4] = (short)f2bf(v1.x); p[5] = (short)f2bf(v1.y);
        p[6] = (short)f2bf(v1.z); p[7] = (short)f2bf(v1.w);
        *(short8*)(out + i) = p;
        return;
    }
    bid -= 4096;
    const float* in; u16* out; int C; size_t moff; int rt, ct;
    if (bid < 768) {
        const int m = bid >> 8, idx = bid & 255;
        in = (m == 0) ? Wq : (m == 1) ? Wk : Wv;
        out = (m == 0) ? Wqt : (m == 1) ? Wkt : Wvt;
        C = 64; rt = (idx & 15) * 64; ct = 0; moff = (size_t)(idx >> 4) * 65536;
    } else {
        const int idx = bid - 768;
        in = Wo; out = Wot; C = 1024; moff = 0;
        rt = (idx & 15) * 64; ct = (idx >> 4) * 64;
    }
    #pragma unroll
    for (int i = 0; i < 4; ++i) {
        int s = i * 256 + t;
        int row = s >> 4, chunk = s & 15;
        float4 v = *(const float4*)(in + moff + (size_t)(rt + row) * C + ct + chunk * 4);
        ls[row][chunk * 4 + 0] = v.x;
        ls[row][chunk * 4 + 1] = v.y;
        ls[row][chunk * 4 + 2] = v.z;
        ls[row][chunk * 4 + 3] = v.w;
    }
    __syncthreads();
    #pragma unroll
    for (int i = 0; i < 2; ++i) {
        int s = i * 256 + t;
        int n = s >> 3, kc = s & 7;
        short8 p;
        #pragma unroll
        for (int j = 0; j < 8; ++j) p[j] = (short)f2bf(ls[kc * 8 + j][n]);
        *(short8*)(out + moff + (size_t)(ct + n) * 1024 + rt + kc * 8) = p;
    }
}

// ---------------------------------------------------------------------------
// m97-style MFMA GEMM core: 256 thr = 4 waves, BM=BN=128, BK=32, K=1024.
// (unchanged from round 6 — gemm_qkv's host)
// ---------------------------------------------------------------------------
__device__ __forceinline__ void gemm_core(
    const u16* __restrict__ A, const u16* __restrict__ Wt,
    int m0, u16* As, u16* Bs, f32x4 (&acc)[4][4])
{
    const int t = threadIdx.x;                 // 0..255
    const int w = t >> 6, lane = t & 63;
    const int quad = lane >> 4, c = lane & 15;
    const int srow = w * 32 + (lane >> 2);     // staging row (of 128)
    const int sch = lane & 3;                  // 8-u16 chunk within 32

    const u16* gA = A + (size_t)(m0 + srow) * 1024 + sch * 8;
    const u16* gB = Wt + (size_t)srow * 1024 + sch * 8;
    u16* lA = As + w * 32 * 32;                // wave-uniform LDS base
    u16* lB = Bs + w * 32 * 32;
    const u16* afr = As + ((w >> 1) * 64 + c) * 32 + quad * 8;
    const u16* bfr = Bs + ((w & 1) * 64 + c) * 32 + quad * 8;

    for (int kt = 0; kt < 1024; kt += 32) {
        glds16(lA,           gA + kt);
        glds16(lA + 16 * 32, gA + kt + 16 * 1024);
        glds16(lB,           gB + kt);
        glds16(lB + 16 * 32, gB + kt + 16 * 1024);
        __syncthreads();
        short8 af[4], bf[4];
        #pragma unroll
        for (int rs = 0; rs < 4; ++rs) af[rs] = *(const short8*)(afr + rs * 16 * 32);
        #pragma unroll
        for (int cs = 0; cs < 4; ++cs) bf[cs] = *(const short8*)(bfr + cs * 16 * 32);
        #pragma unroll
        for (int rs = 0; rs < 4; ++rs)
            #pragma unroll
            for (int cs = 0; cs < 4; ++cs)
                acc[rs][cs] = __builtin_amdgcn_mfma_f32_16x16x32_bf16(
                    af[rs], bf[cs], acc[rs][cs], 0, 0, 0);
        __syncthreads();
    }
}

// ---------------------------------------------------------------------------
// Fused Q/K/V projection. grid (8 ntiles, 32 mtiles, 3 = q/k/v), 256 thr.
// ---------------------------------------------------------------------------
__global__ __launch_bounds__(256, 3) void gemm_qkv(
    const u16* __restrict__ Aq, const u16* __restrict__ Ac,
    const u16* __restrict__ Wqt, const u16* __restrict__ Wkt,
    const u16* __restrict__ Wvt,
    const float* __restrict__ bq, const float* __restrict__ bk,
    const float* __restrict__ bv,
    u16* __restrict__ qws, u16* __restrict__ kws, u16* __restrict__ vtws,
    float* __restrict__ resid)
{
    __shared__ u16 As[128 * 32];
    __shared__ u16 Bs[128 * 32];
    const int n0 = blockIdx.x * 128, m0 = blockIdx.y * 128, z = blockIdx.z;
    const int t = threadIdx.x;
    const int w = t >> 6, lane = t & 63;
    const int quad = lane >> 4, c = lane & 15;

    const u16* A = (z == 0) ? Aq : Ac;
    const u16* Wt = ((z == 0) ? Wqt : (z == 1) ? Wkt : Wvt) + (size_t)n0 * 1024;
    const float* bias = (z == 0) ? bq : (z == 1) ? bk : bv;

    f32x4 acc[4][4] = {};
    gemm_core(A, Wt, m0, As, Bs, acc);

    const int h = blockIdx.x * 2 + (w & 1);
    float bb[4];
    #pragma unroll
    for (int cs = 0; cs < 4; ++cs) bb[cs] = bias[h * 64 + cs * 16 + c];

    if (z == 2) {
        #pragma unroll
        for (int rs = 0; rs < 4; ++rs) {
            const int l0 = m0 + (w >> 1) * 64 + rs * 16 + quad * 4;
            const int b = l0 >> 10, l = l0 & 1023;
            #pragma unroll
            for (int cs = 0; cs < 4; ++cs) {
                const int hd = cs * 16 + c;
                ushort4 pk;
                pk.x = f2bf(acc[rs][cs][0] + bb[cs]);
                pk.y = f2bf(acc[rs][cs][1] + bb[cs]);
                pk.z = f2bf(acc[rs][cs][2] + bb[cs]);
                pk.w = f2bf(acc[rs][cs][3] + bb[cs]);
                *(ushort4*)(vtws + ((size_t)(b * 16 + h) * 64 + hd) * 1024 + l) = pk;
            }
        }
    } else {
        u16* dst = (z == 0) ? qws : kws;
        const float scale = (z == 0) ? 0.125f : 1.0f;
        #pragma unroll
        for (int rs = 0; rs < 4; ++rs) {
            #pragma unroll
            for (int r = 0; r < 4; ++r) {
                const int row = m0 + (w >> 1) * 64 + rs * 16 + quad * 4 + r;
                const int b = row >> 10, l = row & 1023;
                u16* drow = dst + (((size_t)(b * 16 + h) * 1024) + l) * 64;
                float* rrow = (z == 0) ? (resid + (size_t)row * 1024 + h * 64) : nullptr;
                #pragma unroll
                for (int cs = 0; cs < 4; ++cs) {
                    float v = acc[rs][cs][r] + bb[cs];
                    drow[cs * 16 + c] = f2bf(v * scale);
                    if (z == 0) rrow[cs * 16 + c] = v;
                }
            }
        }
    }
}

// ---------------------------------------------------------------------------
// Output projection v2: 128m x 64n tiles, flat grid 512, XCD-aware swizzle
// (XCD = flat%8 owns mtiles 4x..4x+3 for ALL ntiles -> A-slice + Wot stay
// L2-resident per XCD). 2 blocks/CU. Per wave: 64x32 quadrant, acc[4][2].
// ---------------------------------------------------------------------------
__global__ __launch_bounds__(256, 3) void gemm_out(
    const u16* __restrict__ A, const u16* __restrict__ Wot,
    const float* __restrict__ bo, float* __restrict__ out)
{
    __shared__ u16 As[128 * 32];   // 8 KB
    __shared__ u16 Bs[64 * 32];    // 4 KB
    const int f = blockIdx.x;
    const int xcd = f & 7, k = f >> 3;         // k 0..63
    const int m0 = (xcd * 4 + (k & 3)) * 128;  // mtile 0..31
    const int n0 = (k >> 2) * 64;              // ntile 0..15
    const int t = threadIdx.x;
    const int w = t >> 6, lane = t & 63;
    const int quad = lane >> 4, c = lane & 15;

    const int arow = w * 32 + (lane >> 2), ach = lane & 3;
    const int brow = w * 16 + (lane >> 2);
    const u16* gA = A + (size_t)(m0 + arow) * 1024 + ach * 8;
    const u16* gB = Wot + (size_t)(n0 + brow) * 1024 + ach * 8;
    u16* lA = As + w * 32 * 32;
    u16* lB = Bs + w * 16 * 32;
    const u16* afr = As + ((w >> 1) * 64 + c) * 32 + quad * 8;
    const u16* bfr = Bs + ((w & 1) * 32 + c) * 32 + quad * 8;

    f32x4 acc[4][2] = {};
    for (int kt = 0; kt < 1024; kt += 32) {
        glds16(lA,           gA + kt);
        glds16(lA + 16 * 32, gA + kt + 16 * 1024);
        glds16(lB,           gB + kt);
        __syncthreads();
        short8 af[4], bf[2];
        #pragma unroll
        for (int rs = 0; rs < 4; ++rs) af[rs] = *(const short8*)(afr + rs * 16 * 32);
        #pragma unroll
        for (int cs = 0; cs < 2; ++cs) bf[cs] = *(const short8*)(bfr + cs * 16 * 32);
        #pragma unroll
        for (int rs = 0; rs < 4; ++rs)
            #pragma unroll
            for (int cs = 0; cs < 2; ++cs)
                acc[rs][cs] = __builtin_amdgcn_mfma_f32_16x16x32_bf16(
                    af[rs], bf[cs], acc[rs][cs], 0, 0, 0);
        __syncthreads();
    }

    const int nb = n0 + (w & 1) * 32;
    float bb[2];
    #pragma unroll
    for (int cs = 0; cs < 2; ++cs) bb[cs] = bo[nb + cs * 16 + c];

    #pragma unroll
    for (int rs = 0; rs < 4; ++rs) {
        #pragma unroll
        for (int r = 0; r < 4; ++r) {
            const int row = m0 + (w >> 1) * 64 + rs * 16 + quad * 4 + r;
            float* orow = out + (size_t)row * 1024 + nb;
            #pragma unroll
            for (int cs = 0; cs < 2; ++cs)
                orow[cs * 16 + c] = acc[rs][cs][r] + bb[cs];
        }
    }
}

// ---------------------------------------------------------------------------
// MFMA flash attention v4: grid (16, 64), 256 thr = 4 waves (same b,h).
// Cooperative swizzled LDS staging of K/Vt 64-key tiles (as v3). NEW: compute
// S^T = K·Q^T (same fragments, swapped MFMA operand slots) so P emerges in
// C-layout [key][q]; PV A-fragment built IN-REGISTER via 16 __shfl + selects
// (replaces the P->LDS round-trip). l-sum reduced once in epilogue.
// ---------------------------------------------------------------------------
__global__ __launch_bounds__(256, 4) void attn_mfma(
    const u16* __restrict__ qws, const u16* __restrict__ kws,
    const u16* __restrict__ vtws, u16* __restrict__ multi)
{
    __shared__ u16 Ks[64 * 64];        // [key][dim], chunk-swizzled
    __shared__ u16 Vs[64 * 64];        // [dim][key], chunk-swizzled
    const int t = threadIdx.x;
    const int wave = t >> 6, lane = t & 63;
    const int quad = lane >> 4, c = lane & 15;
    const int bh = blockIdx.y, b = bh >> 4, h = bh & 15;
    const int q0 = blockIdx.x * 64 + wave * 16;

    const u16* qb = qws + ((size_t)bh * 1024 + q0) * 64;
    const u16* kb = kws + (size_t)bh * 65536;
    const u16* vb = vtws + (size_t)bh * 65536;

    // Q frags (used as MFMA B-operand): lane holds Q[q0+c][dh*32+quad*8..+7]
    short8 qa0 = *(const short8*)(qb + (size_t)c * 64 + quad * 8);
    short8 qa1 = *(const short8*)(qb + (size_t)c * 64 + 32 + quad * 8);

    // staging (v3): wave stages rows wave*16..+15; lane -> row base+(lane>>3),
    // lds chunk lane&7, global chunk (lane&7)^(row&7)
    const int srow = wave * 16 + (lane >> 3);
    const int gch = (lane & 7) ^ ((lane >> 3) & 7);
    u16* ldsK0 = Ks + (wave * 16) * 64;
    u16* ldsK1 = Ks + (wave * 16 + 8) * 64;
    u16* ldsV0 = Vs + (wave * 16) * 64;
    u16* ldsV1 = Vs + (wave * 16 + 8) * 64;
    const u16* gK0 = kb + (size_t)srow * 64 + gch * 8;
    const u16* gK1 = kb + (size_t)(srow + 8) * 64 + gch * 8;
    const u16* gV0 = vb + (size_t)srow * 1024 + gch * 8;
    const u16* gV1 = vb + (size_t)(srow + 8) * 1024 + gch * 8;

    f32x4 O[4] = {};
    float lsum = 0.f;                  // per-lane: q = c, keys of own quads
    const int cx = c & 7;

    for (int kt = 0; kt < 1024; kt += 64) {
        glds16(ldsK0, gK0 + (size_t)kt * 64);
        glds16(ldsK1, gK1 + (size_t)kt * 64);
        glds16(ldsV0, gV0 + kt);
        glds16(ldsV1, gV1 + kt);
        __syncthreads();                         // vmcnt drained -> tiles valid

        #pragma unroll
        for (int hb = 0; hb < 2; ++hb) {         // 32-key halves
            const int kbase = hb * 32;
            // S^T frags: st0 = keys kbase..+15, st1 = keys kbase+16..+31
            // A-operand = K rows (lane holds K[key][d-chunk]), B = Q frags
            const u16* kr0 = Ks + (kbase + c) * 64;
            const u16* kr1 = Ks + (kbase + 16 + c) * 64;
            short8 kf00 = *(const short8*)(kr0 + (quad ^ cx) * 8);
            short8 kf01 = *(const short8*)(kr0 + ((4 + quad) ^ cx) * 8);
            short8 kf10 = *(const short8*)(kr1 + (quad ^ cx) * 8);
            short8 kf11 = *(const short8*)(kr1 + ((4 + quad) ^ cx) * 8);

            f32x4 st0 = {}, st1 = {};
            st0 = __builtin_amdgcn_mfma_f32_16x16x32_bf16(kf00, qa0, st0, 0, 0, 0);
            st0 = __builtin_amdgcn_mfma_f32_16x16x32_bf16(kf01, qa1, st0, 0, 0, 0);
            st1 = __builtin_amdgcn_mfma_f32_16x16x32_bf16(kf10, qa0, st1, 0, 0, 0);
            st1 = __builtin_amdgcn_mfma_f32_16x16x32_bf16(kf11, qa1, st1, 0, 0, 0);

            // p = exp(s^T): lane (quad,c) holds P[q=c][key kbase+quad*4+r (+16)]
            f32x4 p0, p1;
            #pragma unroll
            for (int r = 0; r < 4; ++r) {
                p0[r] = __expf(st0[r]);
                p1[r] = __expf(st1[r]);
                lsum += p0[r] + p1[r];
            }

            // PV A-frag in-register: lane (quad,c) needs P[q=c][kbase+quad*8+j]
            short8 pa;
            #pragma unroll
            for (int j = 0; j < 8; ++j) {
                const int srcl = ((2 * quad + (j >> 2)) & 3) * 16 + c;
                float v0 = __shfl(p0[j & 3], srcl);
                float v1 = __shfl(p1[j & 3], srcl);
                float v = (quad < 2) ? v0 : v1;
                pa[j] = (short)(__float_as_uint(v) >> 16);
            }

            // B-operand = V: lane holds V[kbase+quad*8+j][d=nt*16+c]
            #pragma unroll
            for (int nt = 0; nt < 4; ++nt) {
                const u16* vr = Vs + (nt * 16 + c) * 64;
                short8 vf = *(const short8*)(vr + ((hb * 4 + quad) ^ cx) * 8);
                O[nt] = __builtin_amdgcn_mfma_f32_16x16x32_bf16(pa, vf, O[nt], 0, 0, 0);
            }
        }
        __syncthreads();                         // frag reads done before restage
    }

    // l-sum: reduce over quads (each lane then holds total for q=c), then
    // broadcast to the lanes holding O rows q=quad*4+r
    lsum += __shfl_xor(lsum, 16);
    lsum += __shfl_xor(lsum, 32);
    float inv[4];
    #pragma unroll
    for (int r = 0; r < 4; ++r) inv[r] = 1.0f / __shfl(lsum, quad * 4 + r);

    u16* ob = multi + ((size_t)b * 1024 + q0 + quad * 4) * 1024 + h * 64 + c;
    #pragma unroll
    for (int r = 0; r < 4; ++r) {
        u16* orow = ob + (size_t)r * 1024;
        orow[0]  = f2bf(O[0][r] * inv[r]);
        orow[16] = f2bf(O[1][r] * inv[r]);
        orow[32] = f2bf(O[2][r] * inv[r]);
        orow[48] = f2bf(O[3][r] * inv[r]);
    }
}

extern "C" void kernel_launch(void* const* d_in, const int* in_sizes, int n_in,
                              void* d_out, int out_size, void* d_ws, size_t ws_size,
                              hipStream_t stream) {
    const float* queries = (const float*)d_in[0];
    const float* context = (const float*)d_in[1];
    const float* Wq = (const float*)d_in[2];
    const float* bq = (const float*)d_in[3];
    const float* Wk = (const float*)d_in[4];
    const float* bk = (const float*)d_in[5];
    const float* Wv = (const float*)d_in[6];
    const float* bv = (const float*)d_in[7];
    const float* Wo = (const float*)d_in[8];
    const float* bo = (const float*)d_in[9];

    float* out = (float*)d_out;                     // [4,1024,1024] f32
    float* resid = out + (size_t)4 * 1024 * 1024;   // [4,1024,1024] f32

    const size_t M1 = 1024 * 1024;
    u16* Aq   = (u16*)d_ws;          // 4M
    u16* Ac   = Aq + 4 * M1;         // 4M
    u16* Wqt  = Ac + 4 * M1;         // 1M
    u16* Wkt  = Wqt + M1;            // 1M
    u16* Wvt  = Wkt + M1;            // 1M
    u16* Wot  = Wvt + M1;            // 1M
    u16* qws  = Wot + M1;            // 4M (pre-scaled 0.125)
    u16* kws  = qws + 4 * M1;        // 4M
    u16* vtws = kws + 4 * M1;        // 4M [B,H,64,1024]
    u16* mws  = vtws + 4 * M1;       // 4M [B,1024,1024]

    prep<<<5120, 256, 0, stream>>>(queries, context, Wq, Wk, Wv, Wo,
                                   Aq, Ac, Wqt, Wkt, Wvt, Wot);
    gemm_qkv<<<dim3(8, 32, 3), 256, 0, stream>>>(Aq, Ac, Wqt, Wkt, Wvt,
                                                 bq, bk, bv, qws, kws, vtws, resid);
    attn_mfma<<<dim3(16, 64), 256, 0, stream>>>(qws, kws, vtws, mws);
    gemm_out<<<512, 256, 0, stream>>>(mws, Wot, bo, out);
}

// Round 8
// 202.129 us; speedup vs baseline: 1.0488x; 1.0488x over previous
//
#include <hip/hip_runtime.h>
#include <hip/hip_bf16.h>

// Shapes: B=4, LQ=LKV=1024, D=1024, H=16, HD=64, N=H*HD=1024, M=B*LQ=4096
// Inputs  (f32): queries[4,1024,1024], context[4,1024,1024],
//   Wq/Wk/Wv[16,1024,64], bq/bk/bv[16,64], Wo[1024,1024], bo[1024]
// Outputs (f32, concat): out[4,1024,1024], residual[4,1024,1024]
// ws (u16, 56 MB): Aq 4M | Ac 4M | Wqt 1M | Wkt 1M | Wvt 1M | Wot 1M |
//                  qws 4M (x0.125) | kws 4M | vtws 4M (dim-major) | mws 4M

typedef unsigned short u16;
typedef __attribute__((ext_vector_type(8))) short short8;   // 8 bf16 = 4 VGPRs
typedef __attribute__((ext_vector_type(4))) float f32x4;

__device__ __forceinline__ float bf2f(u16 u) {
    union { unsigned int i; float f; } c;
    c.i = ((unsigned int)u) << 16;
    return c.f;
}

__device__ __forceinline__ u16 f2bf(float f) {
    unsigned int x = __float_as_uint(f);
    unsigned int r = (x + 0x7fffu + ((x >> 16) & 1u)) >> 16;  // RNE
    return (u16)r;
}

// async global->LDS, 16B per lane; LDS dest = wave-uniform base + lane*16
__device__ __forceinline__ void glds16(u16* lds, const u16* g) {
    __builtin_amdgcn_global_load_lds(
        (const __attribute__((address_space(1))) void*)g,
        (__attribute__((address_space(3))) void*)lds, 16, 0, 0);
}

// ---------------------------------------------------------------------------
// Fused pre-pass, flat grid 5120 blocks x 256 thr (unchanged from round 7)
// ---------------------------------------------------------------------------
__global__ __launch_bounds__(256) void prep(
    const float* __restrict__ q, const float* __restrict__ ctx,
    const float* __restrict__ Wq, const float* __restrict__ Wk,
    const float* __restrict__ Wv, const float* __restrict__ Wo,
    u16* __restrict__ Aq, u16* __restrict__ Ac,
    u16* __restrict__ Wqt, u16* __restrict__ Wkt,
    u16* __restrict__ Wvt, u16* __restrict__ Wot)
{
    __shared__ float ls[64][65];
    const int t = threadIdx.x;
    int bid = blockIdx.x;

    if (bid < 4096) {
        const float* in = (bid < 2048) ? q : ctx;
        u16* out = (bid < 2048) ? Aq : Ac;
        size_t i = ((size_t)(bid & 2047) * 256 + t) * 8;
        float4 v0 = *(const float4*)(in + i);
        float4 v1 = *(const float4*)(in + i + 4);
        short8 p;
        p[0] = (short)f2bf(v0.x); p[1] = (short)f2bf(v0.y);
        p[2] = (short)f2bf(v0.z); p[3] = (short)f2bf(v0.w);
        p[4] = (short)f2bf(v1.x); p[5] = (short)f2bf(v1.y);
        p[6] = (short)f2bf(v1.z); p[7] = (short)f2bf(v1.w);
        *(short8*)(out + i) = p;
        return;
    }
    bid -= 4096;
    const float* in; u16* out; int C; size_t moff; int rt, ct;
    if (bid < 768) {
        const int m = bid >> 8, idx = bid & 255;
        in = (m == 0) ? Wq : (m == 1) ? Wk : Wv;
        out = (m == 0) ? Wqt : (m == 1) ? Wkt : Wvt;
        C = 64; rt = (idx & 15) * 64; ct = 0; moff = (size_t)(idx >> 4) * 65536;
    } else {
        const int idx = bid - 768;
        in = Wo; out = Wot; C = 1024; moff = 0;
        rt = (idx & 15) * 64; ct = (idx >> 4) * 64;
    }
    #pragma unroll
    for (int i = 0; i < 4; ++i) {
        int s = i * 256 + t;
        int row = s >> 4, chunk = s & 15;
        float4 v = *(const float4*)(in + moff + (size_t)(rt + row) * C + ct + chunk * 4);
        ls[row][chunk * 4 + 0] = v.x;
        ls[row][chunk * 4 + 1] = v.y;
        ls[row][chunk * 4 + 2] = v.z;
        ls[row][chunk * 4 + 3] = v.w;
    }
    __syncthreads();
    #pragma unroll
    for (int i = 0; i < 2; ++i) {
        int s = i * 256 + t;
        int n = s >> 3, kc = s & 7;
        short8 p;
        #pragma unroll
        for (int j = 0; j < 8; ++j) p[j] = (short)f2bf(ls[kc * 8 + j][n]);
        *(short8*)(out + moff + (size_t)(ct + n) * 1024 + rt + kc * 8) = p;
    }
}

// ---------------------------------------------------------------------------
// Q/K/V projection v2, K+V fused. grid (8 ntiles, 32 mtiles, 2), 256 thr.
// z=0: Q = Aq@Wq (16 MFMA / barrier-pair).  z=1: K AND V from one Ac staging
// (32 MFMA / barrier-pair; halves Ac traffic, amortizes the barrier drain).
// BM=BN=128, BK=32. LDS unpadded (global_load_lds layout). Per-branch
// register scopes keep the Q path lean.
// ---------------------------------------------------------------------------
__global__ __launch_bounds__(256, 2) void gemm_qkv(
    const u16* __restrict__ Aq, const u16* __restrict__ Ac,
    const u16* __restrict__ Wqt, const u16* __restrict__ Wkt,
    const u16* __restrict__ Wvt,
    const float* __restrict__ bq, const float* __restrict__ bk,
    const float* __restrict__ bv,
    u16* __restrict__ qws, u16* __restrict__ kws, u16* __restrict__ vtws,
    float* __restrict__ resid)
{
    __shared__ u16 As[128 * 32];
    __shared__ u16 B1[128 * 32];
    __shared__ u16 B2[128 * 32];
    const int n0 = blockIdx.x * 128, m0 = blockIdx.y * 128, z = blockIdx.z;
    const int t = threadIdx.x;
    const int w = t >> 6, lane = t & 63;
    const int quad = lane >> 4, c = lane & 15;
    const int srow = w * 32 + (lane >> 2);     // staging row (of 128)
    const int sch = lane & 3;                  // 8-u16 chunk within 32

    u16* lA = As + w * 32 * 32;
    u16* lB1 = B1 + w * 32 * 32;
    u16* lB2 = B2 + w * 32 * 32;
    const u16* afr = As + ((w >> 1) * 64 + c) * 32 + quad * 8;
    const u16* b1fr = B1 + ((w & 1) * 64 + c) * 32 + quad * 8;
    const u16* b2fr = B2 + ((w & 1) * 64 + c) * 32 + quad * 8;
    const int h = blockIdx.x * 2 + (w & 1);

    if (z == 0) {
        const u16* gA = Aq + (size_t)(m0 + srow) * 1024 + sch * 8;
        const u16* gB = Wqt + (size_t)(n0 + srow) * 1024 + sch * 8;
        f32x4 acc[4][4] = {};
        for (int kt = 0; kt < 1024; kt += 32) {
            glds16(lA,           gA + kt);
            glds16(lA + 16 * 32, gA + kt + 16 * 1024);
            glds16(lB1,           gB + kt);
            glds16(lB1 + 16 * 32, gB + kt + 16 * 1024);
            __syncthreads();
            short8 af[4], bf[4];
            #pragma unroll
            for (int rs = 0; rs < 4; ++rs) af[rs] = *(const short8*)(afr + rs * 16 * 32);
            #pragma unroll
            for (int cs = 0; cs < 4; ++cs) bf[cs] = *(const short8*)(b1fr + cs * 16 * 32);
            #pragma unroll
            for (int rs = 0; rs < 4; ++rs)
                #pragma unroll
                for (int cs = 0; cs < 4; ++cs)
                    acc[rs][cs] = __builtin_amdgcn_mfma_f32_16x16x32_bf16(
                        af[rs], bf[cs], acc[rs][cs], 0, 0, 0);
            __syncthreads();
        }
        float bb[4];
        #pragma unroll
        for (int cs = 0; cs < 4; ++cs) bb[cs] = bq[h * 64 + cs * 16 + c];
        #pragma unroll
        for (int rs = 0; rs < 4; ++rs)
            #pragma unroll
            for (int r = 0; r < 4; ++r) {
                const int row = m0 + (w >> 1) * 64 + rs * 16 + quad * 4 + r;
                const int b = row >> 10, l = row & 1023;
                u16* drow = qws + (((size_t)(b * 16 + h) * 1024) + l) * 64;
                float* rrow = resid + (size_t)row * 1024 + h * 64;
                #pragma unroll
                for (int cs = 0; cs < 4; ++cs) {
                    float v = acc[rs][cs][r] + bb[cs];
                    drow[cs * 16 + c] = f2bf(v * 0.125f);
                    rrow[cs * 16 + c] = v;
                }
            }
    } else {
        const u16* gA = Ac + (size_t)(m0 + srow) * 1024 + sch * 8;
        const u16* gBk = Wkt + (size_t)(n0 + srow) * 1024 + sch * 8;
        const u16* gBv = Wvt + (size_t)(n0 + srow) * 1024 + sch * 8;
        f32x4 acck[4][4] = {};
        f32x4 accv[4][4] = {};
        for (int kt = 0; kt < 1024; kt += 32) {
            glds16(lA,            gA + kt);
            glds16(lA + 16 * 32,  gA + kt + 16 * 1024);
            glds16(lB1,           gBk + kt);
            glds16(lB1 + 16 * 32, gBk + kt + 16 * 1024);
            glds16(lB2,           gBv + kt);
            glds16(lB2 + 16 * 32, gBv + kt + 16 * 1024);
            __syncthreads();
            short8 af[4], bkf[4], bvf[4];
            #pragma unroll
            for (int rs = 0; rs < 4; ++rs) af[rs] = *(const short8*)(afr + rs * 16 * 32);
            #pragma unroll
            for (int cs = 0; cs < 4; ++cs) {
                bkf[cs] = *(const short8*)(b1fr + cs * 16 * 32);
                bvf[cs] = *(const short8*)(b2fr + cs * 16 * 32);
            }
            #pragma unroll
            for (int rs = 0; rs < 4; ++rs)
                #pragma unroll
                for (int cs = 0; cs < 4; ++cs) {
                    acck[rs][cs] = __builtin_amdgcn_mfma_f32_16x16x32_bf16(
                        af[rs], bkf[cs], acck[rs][cs], 0, 0, 0);
                    accv[rs][cs] = __builtin_amdgcn_mfma_f32_16x16x32_bf16(
                        af[rs], bvf[cs], accv[rs][cs], 0, 0, 0);
                }
            __syncthreads();
        }
        float bbk[4], bbv[4];
        #pragma unroll
        for (int cs = 0; cs < 4; ++cs) {
            bbk[cs] = bk[h * 64 + cs * 16 + c];
            bbv[cs] = bv[h * 64 + cs * 16 + c];
        }
        #pragma unroll
        for (int rs = 0; rs < 4; ++rs) {
            // K: kws [B,H,1024,64]
            #pragma unroll
            for (int r = 0; r < 4; ++r) {
                const int row = m0 + (w >> 1) * 64 + rs * 16 + quad * 4 + r;
                const int b = row >> 10, l = row & 1023;
                u16* drow = kws + (((size_t)(b * 16 + h) * 1024) + l) * 64;
                #pragma unroll
                for (int cs = 0; cs < 4; ++cs)
                    drow[cs * 16 + c] = f2bf(acck[rs][cs][r] + bbk[cs]);
            }
            // V: vtws [B,H,64,1024]; 4 acc regs = 4 consecutive l -> ushort4
            const int l0 = m0 + (w >> 1) * 64 + rs * 16 + quad * 4;
            const int b = l0 >> 10, l = l0 & 1023;
            #pragma unroll
            for (int cs = 0; cs < 4; ++cs) {
                const int hd = cs * 16 + c;
                ushort4 pk;
                pk.x = f2bf(accv[rs][cs][0] + bbv[cs]);
                pk.y = f2bf(accv[rs][cs][1] + bbv[cs]);
                pk.z = f2bf(accv[rs][cs][2] + bbv[cs]);
                pk.w = f2bf(accv[rs][cs][3] + bbv[cs]);
                *(ushort4*)(vtws + ((size_t)(b * 16 + h) * 64 + hd) * 1024 + l) = pk;
            }
        }
    }
}

// ---------------------------------------------------------------------------
// Output projection v2 (unchanged from round 7): 128m x 64n, flat grid 512,
// XCD-aware swizzle, 2 blocks/CU.
// ---------------------------------------------------------------------------
__global__ __launch_bounds__(256, 3) void gemm_out(
    const u16* __restrict__ A, const u16* __restrict__ Wot,
    const float* __restrict__ bo, float* __restrict__ out)
{
    __shared__ u16 As[128 * 32];   // 8 KB
    __shared__ u16 Bs[64 * 32];    // 4 KB
    const int f = blockIdx.x;
    const int xcd = f & 7, k = f >> 3;
    const int m0 = (xcd * 4 + (k & 3)) * 128;
    const int n0 = (k >> 2) * 64;
    const int t = threadIdx.x;
    const int w = t >> 6, lane = t & 63;
    const int quad = lane >> 4, c = lane & 15;

    const int arow = w * 32 + (lane >> 2), ach = lane & 3;
    const int brow = w * 16 + (lane >> 2);
    const u16* gA = A + (size_t)(m0 + arow) * 1024 + ach * 8;
    const u16* gB = Wot + (size_t)(n0 + brow) * 1024 + ach * 8;
    u16* lA = As + w * 32 * 32;
    u16* lB = Bs + w * 16 * 32;
    const u16* afr = As + ((w >> 1) * 64 + c) * 32 + quad * 8;
    const u16* bfr = Bs + ((w & 1) * 32 + c) * 32 + quad * 8;

    f32x4 acc[4][2] = {};
    for (int kt = 0; kt < 1024; kt += 32) {
        glds16(lA,           gA + kt);
        glds16(lA + 16 * 32, gA + kt + 16 * 1024);
        glds16(lB,           gB + kt);
        __syncthreads();
        short8 af[4], bf[2];
        #pragma unroll
        for (int rs = 0; rs < 4; ++rs) af[rs] = *(const short8*)(afr + rs * 16 * 32);
        #pragma unroll
        for (int cs = 0; cs < 2; ++cs) bf[cs] = *(const short8*)(bfr + cs * 16 * 32);
        #pragma unroll
        for (int rs = 0; rs < 4; ++rs)
            #pragma unroll
            for (int cs = 0; cs < 2; ++cs)
                acc[rs][cs] = __builtin_amdgcn_mfma_f32_16x16x32_bf16(
                    af[rs], bf[cs], acc[rs][cs], 0, 0, 0);
        __syncthreads();
    }

    const int nb = n0 + (w & 1) * 32;
    float bb[2];
    #pragma unroll
    for (int cs = 0; cs < 2; ++cs) bb[cs] = bo[nb + cs * 16 + c];

    #pragma unroll
    for (int rs = 0; rs < 4; ++rs) {
        #pragma unroll
        for (int r = 0; r < 4; ++r) {
            const int row = m0 + (w >> 1) * 64 + rs * 16 + quad * 4 + r;
            float* orow = out + (size_t)row * 1024 + nb;
            #pragma unroll
            for (int cs = 0; cs < 2; ++cs)
                orow[cs * 16 + c] = acc[rs][cs][r] + bb[cs];
        }
    }
}

// ---------------------------------------------------------------------------
// MFMA flash attention v3 (revert of v4 — round 5's version, known 40 µs):
// cooperative swizzled LDS staging of K/Vt 64-key tiles; S=Q·K^T, unshifted
// exp, P->per-wave LDS round-trip, O+=P·V. Deferred row-sum.
// ---------------------------------------------------------------------------
__global__ __launch_bounds__(256, 4) void attn_mfma(
    const u16* __restrict__ qws, const u16* __restrict__ kws,
    const u16* __restrict__ vtws, u16* __restrict__ multi)
{
    __shared__ u16 Ks[64 * 64];        // [key][dim], chunk-swizzled
    __shared__ u16 Vs[64 * 64];        // [dim][key], chunk-swizzled
    __shared__ u16 Ps[4][16 * 72];     // per-wave P, row stride 72 u16
    const int t = threadIdx.x;
    const int wave = t >> 6, lane = t & 63;
    const int quad = lane >> 4, c = lane & 15;
    const int bh = blockIdx.y, b = bh >> 4, h = bh & 15;
    const int q0 = blockIdx.x * 64 + wave * 16;

    const u16* qb = qws + ((size_t)bh * 1024 + q0) * 64;
    const u16* kb = kws + (size_t)bh * 65536;
    const u16* vb = vtws + (size_t)bh * 65536;

    short8 qa0 = *(const short8*)(qb + (size_t)c * 64 + quad * 8);
    short8 qa1 = *(const short8*)(qb + (size_t)c * 64 + 32 + quad * 8);

    const int srow = wave * 16 + (lane >> 3);
    const int gch = (lane & 7) ^ ((lane >> 3) & 7);
    u16* ldsK0 = Ks + (wave * 16) * 64;
    u16* ldsK1 = Ks + (wave * 16 + 8) * 64;
    u16* ldsV0 = Vs + (wave * 16) * 64;
    u16* ldsV1 = Vs + (wave * 16 + 8) * 64;
    const u16* gK0 = kb + (size_t)srow * 64 + gch * 8;
    const u16* gK1 = kb + (size_t)(srow + 8) * 64 + gch * 8;
    const u16* gV0 = vb + (size_t)srow * 1024 + gch * 8;
    const u16* gV1 = vb + (size_t)(srow + 8) * 1024 + gch * 8;

    f32x4 O[4] = {};
    float ps[4] = {0.f, 0.f, 0.f, 0.f};
    u16* pw = &Ps[wave][0];
    const int cx = c & 7;

    for (int kt = 0; kt < 1024; kt += 64) {
        glds16(ldsK0, gK0 + (size_t)kt * 64);
        glds16(ldsK1, gK1 + (size_t)kt * 64);
        glds16(ldsV0, gV0 + kt);
        glds16(ldsV1, gV1 + kt);
        __syncthreads();                         // vmcnt drained -> tiles valid

        f32x4 s[4];
        #pragma unroll
        for (int nt = 0; nt < 4; ++nt) {
            const u16* kr = Ks + (nt * 16 + c) * 64;
            short8 kb0 = *(const short8*)(kr + ((quad ^ cx)) * 8);
            short8 kb1 = *(const short8*)(kr + (((4 + quad) ^ cx)) * 8);
            f32x4 z = {};
            z = __builtin_amdgcn_mfma_f32_16x16x32_bf16(qa0, kb0, z, 0, 0, 0);
            z = __builtin_amdgcn_mfma_f32_16x16x32_bf16(qa1, kb1, z, 0, 0, 0);
            s[nt] = z;
        }

        #pragma unroll
        for (int nt = 0; nt < 4; ++nt)
            #pragma unroll
            for (int r = 0; r < 4; ++r) {
                float p = __expf(s[nt][r]);
                ps[r] += p;
                pw[(quad * 4 + r) * 72 + nt * 16 + c] = (u16)(__float_as_uint(p) >> 16);
            }
        short8 pa0 = *(const short8*)(pw + c * 72 + quad * 8);
        short8 pa1 = *(const short8*)(pw + c * 72 + 32 + quad * 8);

        #pragma unroll
        for (int nt = 0; nt < 4; ++nt) {
            const u16* vr = Vs + (nt * 16 + c) * 64;
            short8 vb0 = *(const short8*)(vr + ((quad ^ cx)) * 8);
            short8 vb1 = *(const short8*)(vr + (((4 + quad) ^ cx)) * 8);
            O[nt] = __builtin_amdgcn_mfma_f32_16x16x32_bf16(pa0, vb0, O[nt], 0, 0, 0);
            O[nt] = __builtin_amdgcn_mfma_f32_16x16x32_bf16(pa1, vb1, O[nt], 0, 0, 0);
        }
        __syncthreads();                         // frag reads done before restage
    }

    float inv[4];
    #pragma unroll
    for (int r = 0; r < 4; ++r) {
        float sum = ps[r];
        sum += __shfl_xor(sum, 1);
        sum += __shfl_xor(sum, 2);
        sum += __shfl_xor(sum, 4);
        sum += __shfl_xor(sum, 8);
        inv[r] = 1.0f / sum;
    }

    u16* ob = multi + ((size_t)b * 1024 + q0 + quad * 4) * 1024 + h * 64 + c;
    #pragma unroll
    for (int r = 0; r < 4; ++r) {
        u16* orow = ob + (size_t)r * 1024;
        orow[0]  = f2bf(O[0][r] * inv[r]);
        orow[16] = f2bf(O[1][r] * inv[r]);
        orow[32] = f2bf(O[2][r] * inv[r]);
        orow[48] = f2bf(O[3][r] * inv[r]);
    }
}

extern "C" void kernel_launch(void* const* d_in, const int* in_sizes, int n_in,
                              void* d_out, int out_size, void* d_ws, size_t ws_size,
                              hipStream_t stream) {
    const float* queries = (const float*)d_in[0];
    const float* context = (const float*)d_in[1];
    const float* Wq = (const float*)d_in[2];
    const float* bq = (const float*)d_in[3];
    const float* Wk = (const float*)d_in[4];
    const float* bk = (const float*)d_in[5];
    const float* Wv = (const float*)d_in[6];
    const float* bv = (const float*)d_in[7];
    const float* Wo = (const float*)d_in[8];
    const float* bo = (const float*)d_in[9];

    float* out = (float*)d_out;                     // [4,1024,1024] f32
    float* resid = out + (size_t)4 * 1024 * 1024;   // [4,1024,1024] f32

    const size_t M1 = 1024 * 1024;
    u16* Aq   = (u16*)d_ws;          // 4M
    u16* Ac   = Aq + 4 * M1;         // 4M
    u16* Wqt  = Ac + 4 * M1;         // 1M
    u16* Wkt  = Wqt + M1;            // 1M
    u16* Wvt  = Wkt + M1;            // 1M
    u16* Wot  = Wvt + M1;            // 1M
    u16* qws  = Wot + M1;            // 4M (pre-scaled 0.125)
    u16* kws  = qws + 4 * M1;        // 4M
    u16* vtws = kws + 4 * M1;        // 4M [B,H,64,1024]
    u16* mws  = vtws + 4 * M1;       // 4M [B,1024,1024]

    prep<<<5120, 256, 0, stream>>>(queries, context, Wq, Wk, Wv, Wo,
                                   Aq, Ac, Wqt, Wkt, Wvt, Wot);
    gemm_qkv<<<dim3(8, 32, 2), 256, 0, stream>>>(Aq, Ac, Wqt, Wkt, Wvt,
                                                 bq, bk, bv, qws, kws, vtws, resid);
    attn_mfma<<<dim3(16, 64), 256, 0, stream>>>(qws, kws, vtws, mws);
    gemm_out<<<512, 256, 0, stream>>>(mws, Wot, bo, out);
}

// Round 9
// 201.528 us; speedup vs baseline: 1.0519x; 1.0030x over previous
//
#include <hip/hip_runtime.h>
#include <hip/hip_bf16.h>

// Shapes: B=4, LQ=LKV=1024, D=1024, H=16, HD=64, N=H*HD=1024, M=B*LQ=4096
// Inputs  (f32): queries[4,1024,1024], context[4,1024,1024],
//   Wq/Wk/Wv[16,1024,64], bq/bk/bv[16,64], Wo[1024,1024], bo[1024]
// Outputs (f32, concat): out[4,1024,1024], residual[4,1024,1024]
// ws (u16, 56 MB): Aq 4M | Ac 4M | Wqt 1M | Wkt 1M | Wvt 1M | Wot 1M |
//                  qws 4M (x0.125) | kws 4M | vtws 4M (dim-major) | mws 4M

typedef unsigned short u16;
typedef __attribute__((ext_vector_type(8))) short short8;   // 8 bf16 = 4 VGPRs
typedef __attribute__((ext_vector_type(4))) float f32x4;

__device__ __forceinline__ float bf2f(u16 u) {
    union { unsigned int i; float f; } c;
    c.i = ((unsigned int)u) << 16;
    return c.f;
}

__device__ __forceinline__ u16 f2bf(float f) {
    unsigned int x = __float_as_uint(f);
    unsigned int r = (x + 0x7fffu + ((x >> 16) & 1u)) >> 16;  // RNE
    return (u16)r;
}

// async global->LDS, 16B/lane; lds base MUST be wave-uniform (HW adds lane*16)
__device__ __forceinline__ void glds16(u16* lds, const u16* g) {
    __builtin_amdgcn_global_load_lds(
        (const __attribute__((address_space(1))) void*)g,
        (__attribute__((address_space(3))) void*)lds, 16, 0, 0);
}

// ---------------------------------------------------------------------------
// Fused pre-pass, flat grid 5120 blocks x 256 thr (unchanged)
// ---------------------------------------------------------------------------
__global__ __launch_bounds__(256) void prep(
    const float* __restrict__ q, const float* __restrict__ ctx,
    const float* __restrict__ Wq, const float* __restrict__ Wk,
    const float* __restrict__ Wv, const float* __restrict__ Wo,
    u16* __restrict__ Aq, u16* __restrict__ Ac,
    u16* __restrict__ Wqt, u16* __restrict__ Wkt,
    u16* __restrict__ Wvt, u16* __restrict__ Wot)
{
    __shared__ float ls[64][65];
    const int t = threadIdx.x;
    int bid = blockIdx.x;

    if (bid < 4096) {
        const float* in = (bid < 2048) ? q : ctx;
        u16* out = (bid < 2048) ? Aq : Ac;
        size_t i = ((size_t)(bid & 2047) * 256 + t) * 8;
        float4 v0 = *(const float4*)(in + i);
        float4 v1 = *(const float4*)(in + i + 4);
        short8 p;
        p[0] = (short)f2bf(v0.x); p[1] = (short)f2bf(v0.y);
        p[2] = (short)f2bf(v0.z); p[3] = (short)f2bf(v0.w);
        p[4] = (short)f2bf(v1.x); p[5] = (short)f2bf(v1.y);
        p[6] = (short)f2bf(v1.z); p[7] = (short)f2bf(v1.w);
        *(short8*)(out + i) = p;
        return;
    }
    bid -= 4096;
    const float* in; u16* out; int C; size_t moff; int rt, ct;
    if (bid < 768) {
        const int m = bid >> 8, idx = bid & 255;
        in = (m == 0) ? Wq : (m == 1) ? Wk : Wv;
        out = (m == 0) ? Wqt : (m == 1) ? Wkt : Wvt;
        C = 64; rt = (idx & 15) * 64; ct = 0; moff = (size_t)(idx >> 4) * 65536;
    } else {
        const int idx = bid - 768;
        in = Wo; out = Wot; C = 1024; moff = 0;
        rt = (idx & 15) * 64; ct = (idx >> 4) * 64;
    }
    #pragma unroll
    for (int i = 0; i < 4; ++i) {
        int s = i * 256 + t;
        int row = s >> 4, chunk = s & 15;
        float4 v = *(const float4*)(in + moff + (size_t)(rt + row) * C + ct + chunk * 4);
        ls[row][chunk * 4 + 0] = v.x;
        ls[row][chunk * 4 + 1] = v.y;
        ls[row][chunk * 4 + 2] = v.z;
        ls[row][chunk * 4 + 3] = v.w;
    }
    __syncthreads();
    #pragma unroll
    for (int i = 0; i < 2; ++i) {
        int s = i * 256 + t;
        int n = s >> 3, kc = s & 7;
        short8 p;
        #pragma unroll
        for (int j = 0; j < 8; ++j) p[j] = (short)f2bf(ls[kc * 8 + j][n]);
        *(short8*)(out + moff + (size_t)(ct + n) * 1024 + rt + kc * 8) = p;
    }
}

// ---------------------------------------------------------------------------
// Q/K/V projection v3: balanced 3-way, BK=64, XOR-swizzled LDS.
// grid (8 ntiles, 32 mtiles, 3 = q/k/v), 256 thr = 4 waves, BM=BN=128.
// LDS [128][64] u16, chunk' = chunk ^ (row&7): glds16 stays coalesced
// (lane group of 8 covers one row permuted), b128 frag reads spread across
// all bank groups (2-way only). 16 barrier-pairs (vs 32 at BK=32).
// No resid write here (attn writes it).
// ---------------------------------------------------------------------------
__global__ __launch_bounds__(256) void gemm_qkv(
    const u16* __restrict__ Aq, const u16* __restrict__ Ac,
    const u16* __restrict__ Wqt, const u16* __restrict__ Wkt,
    const u16* __restrict__ Wvt,
    const float* __restrict__ bq, const float* __restrict__ bk,
    const float* __restrict__ bv,
    u16* __restrict__ qws, u16* __restrict__ kws, u16* __restrict__ vtws)
{
    __shared__ u16 As[128 * 64];   // 16 KB
    __shared__ u16 Bs[128 * 64];   // 16 KB
    const int n0 = blockIdx.x * 128, m0 = blockIdx.y * 128, z = blockIdx.z;
    const int t = threadIdx.x;
    const int w = t >> 6, lane = t & 63;
    const int quad = lane >> 4, c = lane & 15;
    const int cx = c & 7;

    const u16* A = (z == 0) ? Aq : Ac;
    const u16* Wt = ((z == 0) ? Wqt : (z == 1) ? Wkt : Wvt) + (size_t)n0 * 1024;
    const float* bias = (z == 0) ? bq : (z == 1) ? bk : bv;

    // staging: call i covers rows i*32 + w*8 .. +7; lane -> row +(lane>>3),
    // global chunk (lane&7)^(row&7) so LDS chunk slot (lane&7) = swizzled
    const int sr = w * 8 + (lane >> 3);
    const int gch = (lane & 7) ^ ((lane >> 3) & 7);
    const u16* gA = A + (size_t)(m0 + sr) * 1024 + gch * 8;
    const u16* gB = Wt + (size_t)sr * 1024 + gch * 8;

    // fragment rows
    const int arow = (w >> 1) * 64 + c;
    const int brow = (w & 1) * 64 + c;

    f32x4 acc[4][4] = {};

    for (int kt = 0; kt < 1024; kt += 64) {
        #pragma unroll
        for (int i = 0; i < 4; ++i) {
            glds16(As + (i * 32 + w * 8) * 64, gA + (size_t)i * 32 * 1024 + kt);
            glds16(Bs + (i * 32 + w * 8) * 64, gB + (size_t)i * 32 * 1024 + kt);
        }
        __syncthreads();
        #pragma unroll
        for (int kh = 0; kh < 2; ++kh) {
            const int ch = (kh * 4 + quad);
            short8 af[4], bf[4];
            #pragma unroll
            for (int rs = 0; rs < 4; ++rs)
                af[rs] = *(const short8*)(As + (arow + rs * 16) * 64 + (ch ^ cx) * 8);
            #pragma unroll
            for (int cs = 0; cs < 4; ++cs)
                bf[cs] = *(const short8*)(Bs + (brow + cs * 16) * 64 + (ch ^ cx) * 8);
            #pragma unroll
            for (int rs = 0; rs < 4; ++rs)
                #pragma unroll
                for (int cs = 0; cs < 4; ++cs)
                    acc[rs][cs] = __builtin_amdgcn_mfma_f32_16x16x32_bf16(
                        af[rs], bf[cs], acc[rs][cs], 0, 0, 0);
        }
        __syncthreads();
    }

    const int h = blockIdx.x * 2 + (w & 1);
    float bb[4];
    #pragma unroll
    for (int cs = 0; cs < 4; ++cs) bb[cs] = bias[h * 64 + cs * 16 + c];

    if (z == 2) {
        // V: vtws [B,H,64,1024]; 4 acc regs = 4 consecutive l -> ushort4
        #pragma unroll
        for (int rs = 0; rs < 4; ++rs) {
            const int l0 = m0 + (w >> 1) * 64 + rs * 16 + quad * 4;
            const int b = l0 >> 10, l = l0 & 1023;
            #pragma unroll
            for (int cs = 0; cs < 4; ++cs) {
                const int hd = cs * 16 + c;
                ushort4 pk;
                pk.x = f2bf(acc[rs][cs][0] + bb[cs]);
                pk.y = f2bf(acc[rs][cs][1] + bb[cs]);
                pk.z = f2bf(acc[rs][cs][2] + bb[cs]);
                pk.w = f2bf(acc[rs][cs][3] + bb[cs]);
                *(ushort4*)(vtws + ((size_t)(b * 16 + h) * 64 + hd) * 1024 + l) = pk;
            }
        }
    } else {
        u16* dst = (z == 0) ? qws : kws;
        const float scale = (z == 0) ? 0.125f : 1.0f;
        #pragma unroll
        for (int rs = 0; rs < 4; ++rs)
            #pragma unroll
            for (int r = 0; r < 4; ++r) {
                const int row = m0 + (w >> 1) * 64 + rs * 16 + quad * 4 + r;
                const int b = row >> 10, l = row & 1023;
                u16* drow = dst + (((size_t)(b * 16 + h) * 1024) + l) * 64;
                #pragma unroll
                for (int cs = 0; cs < 4; ++cs)
                    drow[cs * 16 + c] = f2bf((acc[rs][cs][r] + bb[cs]) * scale);
            }
    }
}

// ---------------------------------------------------------------------------
// Output projection v3: BK=64, swizzled LDS, 128m x 64n, flat 512, XCD swizzle.
// ---------------------------------------------------------------------------
__global__ __launch_bounds__(256) void gemm_out(
    const u16* __restrict__ A, const u16* __restrict__ Wot,
    const float* __restrict__ bo, float* __restrict__ out)
{
    __shared__ u16 As[128 * 64];   // 16 KB
    __shared__ u16 Bs[64 * 64];    // 8 KB
    const int f = blockIdx.x;
    const int xcd = f & 7, k = f >> 3;
    const int m0 = (xcd * 4 + (k & 3)) * 128;
    const int n0 = (k >> 2) * 64;
    const int t = threadIdx.x;
    const int w = t >> 6, lane = t & 63;
    const int quad = lane >> 4, c = lane & 15;
    const int cx = c & 7;

    const int sr = w * 8 + (lane >> 3);
    const int gch = (lane & 7) ^ ((lane >> 3) & 7);
    const u16* gA = A + (size_t)(m0 + sr) * 1024 + gch * 8;
    const u16* gB = Wot + (size_t)(n0 + sr) * 1024 + gch * 8;

    const int arow = (w >> 1) * 64 + c;
    const int brow = (w & 1) * 32 + c;

    f32x4 acc[4][2] = {};
    for (int kt = 0; kt < 1024; kt += 64) {
        #pragma unroll
        for (int i = 0; i < 4; ++i)
            glds16(As + (i * 32 + w * 8) * 64, gA + (size_t)i * 32 * 1024 + kt);
        #pragma unroll
        for (int i = 0; i < 2; ++i)
            glds16(Bs + (i * 32 + w * 8) * 64, gB + (size_t)i * 32 * 1024 + kt);
        __syncthreads();
        #pragma unroll
        for (int kh = 0; kh < 2; ++kh) {
            const int ch = (kh * 4 + quad);
            short8 af[4], bf[2];
            #pragma unroll
            for (int rs = 0; rs < 4; ++rs)
                af[rs] = *(const short8*)(As + (arow + rs * 16) * 64 + (ch ^ cx) * 8);
            #pragma unroll
            for (int cs = 0; cs < 2; ++cs)
                bf[cs] = *(const short8*)(Bs + (brow + cs * 16) * 64 + (ch ^ cx) * 8);
            #pragma unroll
            for (int rs = 0; rs < 4; ++rs)
                #pragma unroll
                for (int cs = 0; cs < 2; ++cs)
                    acc[rs][cs] = __builtin_amdgcn_mfma_f32_16x16x32_bf16(
                        af[rs], bf[cs], acc[rs][cs], 0, 0, 0);
        }
        __syncthreads();
    }

    const int nb = n0 + (w & 1) * 32;
    float bb[2];
    #pragma unroll
    for (int cs = 0; cs < 2; ++cs) bb[cs] = bo[nb + cs * 16 + c];

    #pragma unroll
    for (int rs = 0; rs < 4; ++rs) {
        #pragma unroll
        for (int r = 0; r < 4; ++r) {
            const int row = m0 + (w >> 1) * 64 + rs * 16 + quad * 4 + r;
            float* orow = out + (size_t)row * 1024 + nb;
            #pragma unroll
            for (int cs = 0; cs < 2; ++cs)
                orow[cs * 16 + c] = acc[rs][cs][r] + bb[cs];
        }
    }
}

// ---------------------------------------------------------------------------
// MFMA flash attention v5 = v3 + XCD-grouped flat grid (xcd = f&7 owns 8
// heads: 2 MB KV working set stays in that XCD's L2) + resid epilogue
// (resid = q_bf16 * 8; x0.125 is pow2 so only q's bf16 rounding remains).
// ---------------------------------------------------------------------------
__global__ __launch_bounds__(256) void attn_mfma(
    const u16* __restrict__ qws, const u16* __restrict__ kws,
    const u16* __restrict__ vtws, u16* __restrict__ multi,
    float* __restrict__ resid)
{
    __shared__ u16 Ks[64 * 64];        // [key][dim], chunk-swizzled
    __shared__ u16 Vs[64 * 64];        // [dim][key], chunk-swizzled
    __shared__ u16 Ps[4][16 * 72];     // per-wave P, row stride 72 u16
    const int t = threadIdx.x;
    const int wave = t >> 6, lane = t & 63;
    const int quad = lane >> 4, c = lane & 15;
    const int f = blockIdx.x;
    const int xcd = f & 7, j = f >> 3;
    const int bh = xcd * 8 + (j & 7);          // 8 heads per XCD
    const int qt = j >> 3;
    const int b = bh >> 4, h = bh & 15;
    const int q0 = qt * 64 + wave * 16;

    const u16* qb = qws + ((size_t)bh * 1024 + q0) * 64;
    const u16* kb = kws + (size_t)bh * 65536;
    const u16* vb = vtws + (size_t)bh * 65536;

    short8 qa0 = *(const short8*)(qb + (size_t)c * 64 + quad * 8);
    short8 qa1 = *(const short8*)(qb + (size_t)c * 64 + 32 + quad * 8);

    const int srow = wave * 16 + (lane >> 3);
    const int gch = (lane & 7) ^ ((lane >> 3) & 7);
    u16* ldsK0 = Ks + (wave * 16) * 64;
    u16* ldsK1 = Ks + (wave * 16 + 8) * 64;
    u16* ldsV0 = Vs + (wave * 16) * 64;
    u16* ldsV1 = Vs + (wave * 16 + 8) * 64;
    const u16* gK0 = kb + (size_t)srow * 64 + gch * 8;
    const u16* gK1 = kb + (size_t)(srow + 8) * 64 + gch * 8;
    const u16* gV0 = vb + (size_t)srow * 1024 + gch * 8;
    const u16* gV1 = vb + (size_t)(srow + 8) * 1024 + gch * 8;

    f32x4 O[4] = {};
    float ps[4] = {0.f, 0.f, 0.f, 0.f};
    u16* pw = &Ps[wave][0];
    const int cx = c & 7;

    for (int kt = 0; kt < 1024; kt += 64) {
        glds16(ldsK0, gK0 + (size_t)kt * 64);
        glds16(ldsK1, gK1 + (size_t)kt * 64);
        glds16(ldsV0, gV0 + kt);
        glds16(ldsV1, gV1 + kt);
        __syncthreads();                         // vmcnt drained -> tiles valid

        f32x4 s[4];
        #pragma unroll
        for (int nt = 0; nt < 4; ++nt) {
            const u16* kr = Ks + (nt * 16 + c) * 64;
            short8 kb0 = *(const short8*)(kr + ((quad ^ cx)) * 8);
            short8 kb1 = *(const short8*)(kr + (((4 + quad) ^ cx)) * 8);
            f32x4 z = {};
            z = __builtin_amdgcn_mfma_f32_16x16x32_bf16(qa0, kb0, z, 0, 0, 0);
            z = __builtin_amdgcn_mfma_f32_16x16x32_bf16(qa1, kb1, z, 0, 0, 0);
            s[nt] = z;
        }

        #pragma unroll
        for (int nt = 0; nt < 4; ++nt)
            #pragma unroll
            for (int r = 0; r < 4; ++r) {
                float p = __expf(s[nt][r]);
                ps[r] += p;
                pw[(quad * 4 + r) * 72 + nt * 16 + c] = (u16)(__float_as_uint(p) >> 16);
            }
        short8 pa0 = *(const short8*)(pw + c * 72 + quad * 8);
        short8 pa1 = *(const short8*)(pw + c * 72 + 32 + quad * 8);

        #pragma unroll
        for (int nt = 0; nt < 4; ++nt) {
            const u16* vr = Vs + (nt * 16 + c) * 64;
            short8 vb0 = *(const short8*)(vr + ((quad ^ cx)) * 8);
            short8 vb1 = *(const short8*)(vr + (((4 + quad) ^ cx)) * 8);
            O[nt] = __builtin_amdgcn_mfma_f32_16x16x32_bf16(pa0, vb0, O[nt], 0, 0, 0);
            O[nt] = __builtin_amdgcn_mfma_f32_16x16x32_bf16(pa1, vb1, O[nt], 0, 0, 0);
        }
        __syncthreads();                         // frag reads done before restage
    }

    float inv[4];
    #pragma unroll
    for (int r = 0; r < 4; ++r) {
        float sum = ps[r];
        sum += __shfl_xor(sum, 1);
        sum += __shfl_xor(sum, 2);
        sum += __shfl_xor(sum, 4);
        sum += __shfl_xor(sum, 8);
        inv[r] = 1.0f / sum;
    }

    u16* ob = multi + ((size_t)b * 1024 + q0 + quad * 4) * 1024 + h * 64 + c;
    #pragma unroll
    for (int r = 0; r < 4; ++r) {
        u16* orow = ob + (size_t)r * 1024;
        orow[0]  = f2bf(O[0][r] * inv[r]);
        orow[16] = f2bf(O[1][r] * inv[r]);
        orow[32] = f2bf(O[2][r] * inv[r]);
        orow[48] = f2bf(O[3][r] * inv[r]);
    }

    // resid epilogue: lane holds Q[q0+c][quad*8..] in qa0/qa1 (scaled 1/8)
    float* rr = resid + ((size_t)b * 1024 + q0 + c) * 1024 + h * 64;
    #pragma unroll
    for (int jj = 0; jj < 8; ++jj) {
        rr[quad * 8 + jj]      = bf2f((u16)qa0[jj]) * 8.0f;
        rr[32 + quad * 8 + jj] = bf2f((u16)qa1[jj]) * 8.0f;
    }
}

extern "C" void kernel_launch(void* const* d_in, const int* in_sizes, int n_in,
                              void* d_out, int out_size, void* d_ws, size_t ws_size,
                              hipStream_t stream) {
    const float* queries = (const float*)d_in[0];
    const float* context = (const float*)d_in[1];
    const float* Wq = (const float*)d_in[2];
    const float* bq = (const float*)d_in[3];
    const float* Wk = (const float*)d_in[4];
    const float* bk = (const float*)d_in[5];
    const float* Wv = (const float*)d_in[6];
    const float* bv = (const float*)d_in[7];
    const float* Wo = (const float*)d_in[8];
    const float* bo = (const float*)d_in[9];

    float* out = (float*)d_out;                     // [4,1024,1024] f32
    float* resid = out + (size_t)4 * 1024 * 1024;   // [4,1024,1024] f32

    const size_t M1 = 1024 * 1024;
    u16* Aq   = (u16*)d_ws;          // 4M
    u16* Ac   = Aq + 4 * M1;         // 4M
    u16* Wqt  = Ac + 4 * M1;         // 1M
    u16* Wkt  = Wqt + M1;            // 1M
    u16* Wvt  = Wkt + M1;            // 1M
    u16* Wot  = Wvt + M1;            // 1M
    u16* qws  = Wot + M1;            // 4M (pre-scaled 0.125)
    u16* kws  = qws + 4 * M1;        // 4M
    u16* vtws = kws + 4 * M1;        // 4M [B,H,64,1024]
    u16* mws  = vtws + 4 * M1;       // 4M [B,1024,1024]

    prep<<<5120, 256, 0, stream>>>(queries, context, Wq, Wk, Wv, Wo,
                                   Aq, Ac, Wqt, Wkt, Wvt, Wot);
    gemm_qkv<<<dim3(8, 32, 3), 256, 0, stream>>>(Aq, Ac, Wqt, Wkt, Wvt,
                                                 bq, bk, bv, qws, kws, vtws);
    attn_mfma<<<1024, 256, 0, stream>>>(qws, kws, vtws, mws, resid);
    gemm_out<<<512, 256, 0, stream>>>(mws, Wot, bo, out);
}